// Round 2
// 436.372 us; speedup vs baseline: 1.0250x; 1.0250x over previous
//
#include <hip/hip_runtime.h>
#include <stdint.h>

#define BB 8
#define SS 2048
#define EE 512
#define INV_SCALE 0.04419417382415922f  // 1/sqrt(512)

typedef __attribute__((ext_vector_type(8))) short bf8_t;   // 8 bf16 in 4 VGPRs
typedef __attribute__((ext_vector_type(4))) float f4_t;    // MFMA accumulator

__device__ __forceinline__ unsigned short f2bf(float f) {
    union { float f; uint32_t u; } x; x.f = f;
    uint32_t r = x.u + 0x7fffu + ((x.u >> 16) & 1u);  // RNE
    return (unsigned short)(r >> 16);
}

// ---------------- prep kernels (unchanged) ----------------

__global__ void __launch_bounds__(256) gather_k_kernel(const int* __restrict__ idx,
                                                       const float* __restrict__ emb,
                                                       unsigned short* __restrict__ out) {
    int id = blockIdx.x * 256 + threadIdx.x;   // B*S*(E/8) = 1,048,576
    int chunk = id & 63;                        // E/8 = 64
    int row = id >> 6;                          // 0..B*S-1
    int e0 = chunk * 8;
    int k = idx[row];
    const float* src = emb + (size_t)k * EE + e0;
    float4 a = *(const float4*)(src);
    float4 c = *(const float4*)(src + 4);
    union { unsigned short s[8]; int4 v; } u;
    u.s[0] = f2bf(a.x); u.s[1] = f2bf(a.y); u.s[2] = f2bf(a.z); u.s[3] = f2bf(a.w);
    u.s[4] = f2bf(c.x); u.s[5] = f2bf(c.y); u.s[6] = f2bf(c.z); u.s[7] = f2bf(c.w);
    *(int4*)(out + (size_t)row * EE + e0) = u.v;
}

__global__ void __launch_bounds__(256) cast_h_kernel(const float* __restrict__ in,
                                                     unsigned short* __restrict__ out) {
    int id = blockIdx.x * 256 + threadIdx.x;   // B*S*E/8 = 1,048,576
    const float* src = in + (size_t)id * 8;
    float4 a = *(const float4*)(src);
    float4 c = *(const float4*)(src + 4);
    union { unsigned short s[8]; int4 v; } u;
    u.s[0] = f2bf(a.x); u.s[1] = f2bf(a.y); u.s[2] = f2bf(a.z); u.s[3] = f2bf(a.w);
    u.s[4] = f2bf(c.x); u.s[5] = f2bf(c.y); u.s[6] = f2bf(c.z); u.s[7] = f2bf(c.w);
    *(int4*)(out + (size_t)id * 8) = u.v;
}

__global__ void __launch_bounds__(256) gather_vt_kernel(const int* __restrict__ idx,
                                                        const float* __restrict__ emb,
                                                        unsigned short* __restrict__ vt) {
    int id = blockIdx.x * 256 + threadIdx.x;   // B*E*S = 8,388,608
    int t = id & (SS - 1);
    int rest = id >> 11;                        // /S
    int e = rest & (EE - 1);
    int b = rest >> 9;                          // /E
    int k = idx[b * SS + t];
    vt[id] = f2bf(emb[(size_t)k * EE + e]);
}

__global__ void __launch_bounds__(256) transpose_w_kernel(const float* __restrict__ w,
                                                          unsigned short* __restrict__ wt) {
    int id = blockIdx.x * 256 + threadIdx.x;   // E*E = 262,144
    int e = id & (EE - 1);
    int f = id >> 9;
    wt[id] = f2bf(w[(size_t)e * EE + f] * INV_SCALE);
}

// ---------------- shared MFMA tile machinery ----------------
// 128x128 output tile, 256 threads = 4 waves in 2x2, wave tile 64x64 = 4x4 of 16x16.
// BK=32. 2-phase double-buffer: stage(t+1) issued BEFORE compute(t); single
// __syncthreads per K-step -> the vmcnt(0) drain lands after the MFMA phase,
// hiding the ~200cy L2 staging latency under compute (T3 minimum form).
// LDS chunk swizzle (rule 21): global_load_lds dest stays LINEAR; the global
// SOURCE 16B-chunk is permuted by c ^= (row>>1)&3, and ds_read applies the same
// XOR to quad. Read bank-group = 4*(R&1) + (quad^((R>>1)&3)) -> each 8-lane
// phase covers all 8 groups -> conflict-free (was 4-8-way, 4.19M conflicts).

__device__ __forceinline__ void stage_tile(const unsigned short* gbase, int ld, int k0,
                                           unsigned short* lds, int wave, int lane) {
    // source chunk pre-swizzle: slot (row, c=lane&3) receives global chunk c ^ ((row>>1)&3);
    // (row>>1)&3 == (lane>>3)&3 since row = i*64 + wave*16 + (lane>>2).
    const int srcchunk = ((lane & 3) ^ ((lane >> 3) & 3)) * 8;
#pragma unroll
    for (int i = 0; i < 2; ++i) {
        int row = i * 64 + wave * 16 + (lane >> 2);
        const unsigned short* g = gbase + (size_t)row * ld + k0 + srcchunk;
        unsigned short* l = lds + i * 2048 + wave * 512 + lane * 8;  // linear: base + lane*16B
        __builtin_amdgcn_global_load_lds((const __attribute__((address_space(1))) unsigned int*)g,
                                         (__attribute__((address_space(3))) unsigned int*)l,
                                         16, 0, 0);
    }
}

template <int KLEN>
__device__ __forceinline__ void mfma_loop(const unsigned short* Abase, int lda,
                                          const unsigned short* Bbase, int ldb,
                                          unsigned short* As, unsigned short* Bs,
                                          f4_t acc[4][4], int wave, int lane) {
    const int wm = wave >> 1, wn = wave & 1, quad = lane >> 4, l16 = lane & 15;
    // read-side swizzle: (R>>1)&3 == (l16>>1)&3 (R = w*64 + mi*16 + l16)
    const int qs = (quad ^ ((l16 >> 1) & 3)) * 8;
    constexpr int NT = KLEN / 32;

    // prologue: stage tile 0 into buffer 0
    stage_tile(Abase, lda, 0, As, wave, lane);
    stage_tile(Bbase, ldb, 0, Bs, wave, lane);
    __syncthreads();

    int cur = 0;
#pragma unroll 1
    for (int t = 0; t < NT; ++t) {
        // issue next-tile staging first (overlaps with ds_read+MFMA below)
        if (t + 1 < NT) {
            stage_tile(Abase, lda, (t + 1) * 32, As + ((cur ^ 1) << 12), wave, lane);
            stage_tile(Bbase, ldb, (t + 1) * 32, Bs + ((cur ^ 1) << 12), wave, lane);
        }
        const unsigned short* a = As + (cur << 12);
        const unsigned short* b = Bs + (cur << 12);
        bf8_t af[4], bfr[4];
#pragma unroll
        for (int mi = 0; mi < 4; ++mi)
            af[mi] = *(const bf8_t*)(a + (wm * 64 + mi * 16 + l16) * 32 + qs);
#pragma unroll
        for (int ni = 0; ni < 4; ++ni)
            bfr[ni] = *(const bf8_t*)(b + (wn * 64 + ni * 16 + l16) * 32 + qs);
#pragma unroll
        for (int mi = 0; mi < 4; ++mi)
#pragma unroll
            for (int ni = 0; ni < 4; ++ni)
                acc[mi][ni] = __builtin_amdgcn_mfma_f32_16x16x32_bf16(af[mi], bfr[ni],
                                                                      acc[mi][ni], 0, 0, 0);
        // single barrier per step: drains vmcnt (next tile ready) + lgkm (reads done)
        __syncthreads();
        cur ^= 1;
    }
}

// ---------------- GEMM kernels ----------------

__global__ void __launch_bounds__(256) qgen_kernel(const unsigned short* __restrict__ H,
                                                   const unsigned short* __restrict__ Wt,
                                                   unsigned short* __restrict__ Q) {
    __shared__ unsigned short As[2 * 128 * 32];
    __shared__ unsigned short Bs[2 * 128 * 32];
    const int tid = threadIdx.x, wave = tid >> 6, lane = tid & 63;
    const int rowT = blockIdx.y;  // 0..127
    const int colT = blockIdx.x;  // 0..3
    f4_t acc[4][4];
    const f4_t z = {0.f, 0.f, 0.f, 0.f};
    for (int i = 0; i < 4; ++i) for (int j = 0; j < 4; ++j) acc[i][j] = z;
    mfma_loop<EE>(H + (size_t)rowT * 128 * EE, EE,
                  Wt + (size_t)colT * 128 * EE, EE, As, Bs, acc, wave, lane);
    const int wm = wave >> 1, wn = wave & 1, quad = lane >> 4, l16 = lane & 15;
#pragma unroll
    for (int mi = 0; mi < 4; ++mi)
#pragma unroll
        for (int r = 0; r < 4; ++r) {
            int row = rowT * 128 + wm * 64 + mi * 16 + quad * 4 + r;
#pragma unroll
            for (int ni = 0; ni < 4; ++ni) {
                int col = colT * 128 + wn * 64 + ni * 16 + l16;
                Q[(size_t)row * EE + col] = f2bf(acc[mi][ni][r]);
            }
        }
}

__global__ void __launch_bounds__(256) qk_kernel(const unsigned short* __restrict__ Q,
                                                 const unsigned short* __restrict__ K,
                                                 const float* __restrict__ mask,
                                                 unsigned short* __restrict__ delta,
                                                 float* __restrict__ lsum) {
    __shared__ unsigned short As[2 * 128 * 32];
    __shared__ unsigned short Bs[2 * 128 * 32];
    const int tid = threadIdx.x, wave = tid >> 6, lane = tid & 63;
    const int b = blockIdx.z, qT = blockIdx.y, tT = blockIdx.x;
    f4_t acc[4][4];
    const f4_t z = {0.f, 0.f, 0.f, 0.f};
    for (int i = 0; i < 4; ++i) for (int j = 0; j < 4; ++j) acc[i][j] = z;
    mfma_loop<EE>(Q + ((size_t)b * SS + qT * 128) * EE, EE,
                  K + ((size_t)b * SS + tT * 128) * EE, EE, As, Bs, acc, wave, lane);
    const int wm = wave >> 1, wn = wave & 1, quad = lane >> 4, l16 = lane & 15;
#pragma unroll
    for (int mi = 0; mi < 4; ++mi)
#pragma unroll
        for (int r = 0; r < 4; ++r) {
            int row = qT * 128 + wm * 64 + mi * 16 + quad * 4 + r;
            const float* mrow = mask + ((size_t)b * SS + row) * SS;
            unsigned short* drow = delta + ((size_t)b * SS + row) * SS;
            float psum = 0.f;
#pragma unroll
            for (int ni = 0; ni < 4; ++ni) {
                int col = tT * 128 + wn * 64 + ni * 16 + l16;
                float m = mrow[col];
                m = fminf(fmaxf(m, 0.f), 1.f);
                float e = __expf(acc[mi][ni][r]) * m;
                drow[col] = f2bf(e);
                psum += e;
            }
#pragma unroll
            for (int off = 1; off < 16; off <<= 1)
                psum += __shfl_xor(psum, off, 16);
            if (l16 == 0) atomicAdd(&lsum[b * SS + row], psum);
        }
}

__global__ void __launch_bounds__(256) pv_kernel(const unsigned short* __restrict__ delta,
                                                 const unsigned short* __restrict__ Vt,
                                                 const float* __restrict__ lsum,
                                                 float* __restrict__ out) {
    __shared__ unsigned short As[2 * 128 * 32];
    __shared__ unsigned short Bs[2 * 128 * 32];
    const int tid = threadIdx.x, wave = tid >> 6, lane = tid & 63;
    const int b = blockIdx.z, qT = blockIdx.y, eT = blockIdx.x;
    f4_t acc[4][4];
    const f4_t z = {0.f, 0.f, 0.f, 0.f};
    for (int i = 0; i < 4; ++i) for (int j = 0; j < 4; ++j) acc[i][j] = z;
    mfma_loop<SS>(delta + ((size_t)b * SS + qT * 128) * SS, SS,
                  Vt + ((size_t)b * EE + eT * 128) * SS, SS, As, Bs, acc, wave, lane);
    const int wm = wave >> 1, wn = wave & 1, quad = lane >> 4, l16 = lane & 15;
#pragma unroll
    for (int mi = 0; mi < 4; ++mi)
#pragma unroll
        for (int r = 0; r < 4; ++r) {
            int row = qT * 128 + wm * 64 + mi * 16 + quad * 4 + r;
            float inv = 1.0f / (lsum[b * SS + row] + 1e-10f);
#pragma unroll
            for (int ni = 0; ni < 4; ++ni) {
                int col = eT * 128 + wn * 64 + ni * 16 + l16;
                out[((size_t)b * SS + row) * EE + col] = acc[mi][ni][r] * inv;
            }
        }
}

// ---------------- launcher ----------------

extern "C" void kernel_launch(void* const* d_in, const int* in_sizes, int n_in,
                              void* d_out, int out_size, void* d_ws, size_t ws_size,
                              hipStream_t stream) {
    const int*   key_seq = (const int*)d_in[0];
    const int*   val_seq = (const int*)d_in[1];
    const float* hidden  = (const float*)d_in[2];
    const float* mask    = (const float*)d_in[3];
    // d_in[4] nan_matrix: unused by forward
    const float* key_emb = (const float*)d_in[5];
    const float* val_emb = (const float*)d_in[6];
    const float* weight  = (const float*)d_in[7];
    float* out = (float*)d_out;

    char* ws = (char*)d_ws;
    const size_t SZ_BSE = (size_t)BB * SS * EE * sizeof(unsigned short);  // 16,777,216
    unsigned short* Q    = (unsigned short*)(ws);
    unsigned short* K    = (unsigned short*)(ws + SZ_BSE);
    unsigned short* Vt   = (unsigned short*)(ws + 2 * SZ_BSE);
    unsigned short* H    = (unsigned short*)(ws + 3 * SZ_BSE);
    unsigned short* Wt   = (unsigned short*)(ws + 4 * SZ_BSE);            // 524,288 B
    float*          lsum = (float*)(ws + 4 * SZ_BSE + 524288);           // 65,536 B
    unsigned short* delta= (unsigned short*)(ws + 4 * SZ_BSE + 524288 + 65536); // 67,108,864 B

    hipMemsetAsync(lsum, 0, (size_t)BB * SS * sizeof(float), stream);

    gather_k_kernel<<<4096, 256, 0, stream>>>(key_seq, key_emb, K);
    cast_h_kernel<<<4096, 256, 0, stream>>>(hidden, H);
    gather_vt_kernel<<<32768, 256, 0, stream>>>(val_seq, val_emb, Vt);
    transpose_w_kernel<<<1024, 256, 0, stream>>>(weight, Wt);

    qgen_kernel<<<dim3(4, 128), 256, 0, stream>>>(H, Wt, Q);
    qk_kernel<<<dim3(16, 16, 8), 256, 0, stream>>>(Q, K, mask, delta, lsum);
    pv_kernel<<<dim3(4, 16, 8), 256, 0, stream>>>(delta, Vt, lsum, out);
}